// Round 1
// baseline (1223.259 us; speedup 1.0000x reference)
//
#include <hip/hip_runtime.h>
#include <math.h>

#define NPIX 9216
#define SCALE 0.17677669529663687f   // 32^-0.5
#define SQRT128 11.313708498984761f

// ws layout (floats): ctxG [64][32][32] at 0 ; sumexpG [64][32] at 65536

__global__ __launch_bounds__(256) void k_init(const float* __restrict__ mem_kv,
                                              float* __restrict__ ctxG,
                                              float* __restrict__ sumexpG) {
  const int bh = blockIdx.x;           // 0..63  (b*4+h)
  const int h = bh & 3;
  const float* mk = mem_kv + h * 128;        // mem_kv[0][h][d][j]
  const float* mv = mem_kv + 512 + h * 128;  // mem_kv[1][h][e][j]
  const int t = threadIdx.x;
  const int d = t >> 3, e0 = (t & 7) * 4;
  float ek[4], se = 0.f;
#pragma unroll
  for (int j = 0; j < 4; ++j) { ek[j] = expf(mk[d * 4 + j]); se += ek[j]; }
#pragma unroll
  for (int ei = 0; ei < 4; ++ei) {
    const int e = e0 + ei;
    float s = 0.f;
#pragma unroll
    for (int j = 0; j < 4; ++j) s += ek[j] * mv[e * 4 + j];
    ctxG[(bh * 32 + d) * 32 + e] = s;   // WRITE (re-init every launch)
  }
  if ((t & 7) == 0) sumexpG[bh * 32 + d] = se;
}

// Fused: rmsnorm + QKV GEMM + q-softmax (-> d_out staging) + exp(k)v^T partial ctx
__global__ __launch_bounds__(256, 2) void k1(
    const float* __restrict__ x, const float* __restrict__ norm_g,
    const float* __restrict__ qkv_w, float* __restrict__ q_out,
    float* __restrict__ ctxG, float* __restrict__ sumexpG) {
  __shared__ float xs[128][36];   // x tile -> xn -> (reused) q tile
  __shared__ float kb[256][36];   // k rows 0..127 (->exp), v rows 128..255
  __shared__ float wch[16][384];  // transposed W chunk: wch[c][o]
  __shared__ float redu[8][32];
  __shared__ float inv[32];

  const int t = threadIdx.x;
  const int b = blockIdx.y;
  const int p0 = blockIdx.x * 32;
  const float* xb = x + ((size_t)b * 128) * NPIX + p0;

  {  // load x tile (128 rows x 32 pixels)
    const int r = t >> 3, c4 = (t & 7) * 4;
#pragma unroll
    for (int pass = 0; pass < 4; ++pass) {
      const int row = pass * 32 + r;
      *(float4*)&xs[row][c4] = *(const float4*)(xb + (size_t)row * NPIX + c4);
    }
  }
  __syncthreads();
  {  // per-pixel sum of squares (partial)
    const int p = t & 31, g = t >> 5;
    float s = 0.f;
#pragma unroll
    for (int i = 0; i < 16; ++i) { const float v = xs[g * 16 + i][p]; s = fmaf(v, v, s); }
    redu[g][p] = s;
  }
  __syncthreads();
  if (t < 32) {
    float s = 0.f;
#pragma unroll
    for (int g = 0; g < 8; ++g) s += redu[g][t];
    inv[t] = SQRT128 / fmaxf(sqrtf(s), 1e-12f);
  }
  __syncthreads();
  {  // xn = x * inv[p] * norm_g[c]
    const int r = t >> 3, c4 = (t & 7) * 4;
#pragma unroll
    for (int pass = 0; pass < 4; ++pass) {
      const int row = pass * 32 + r;
      const float g = norm_g[row];
      float4 v = *(float4*)&xs[row][c4];
      v.x *= inv[c4] * g; v.y *= inv[c4 + 1] * g;
      v.z *= inv[c4 + 2] * g; v.w *= inv[c4 + 3] * g;
      *(float4*)&xs[row][c4] = v;
    }
  }
  // QKV GEMM: thread (og,pg) -> outputs o=og*12..+11, pixels p=pg*4..+3
  const int og = t >> 3, pg = t & 7;
  float acc[12][4];
#pragma unroll
  for (int i = 0; i < 12; ++i)
#pragma unroll
    for (int j = 0; j < 4; ++j) acc[i][j] = 0.f;

  for (int cc = 0; cc < 128; cc += 16) {
    __syncthreads();  // also covers xn-scale visibility on first iter
    for (int g = t; g < 1536; g += 256) {  // stage W chunk, transposed on the fly
      const int o = g >> 2, ci = (g & 3) * 4;
      const float4 w = *(const float4*)(qkv_w + o * 128 + cc + ci);
      wch[ci + 0][o] = w.x; wch[ci + 1][o] = w.y;
      wch[ci + 2][o] = w.z; wch[ci + 3][o] = w.w;
    }
    __syncthreads();
#pragma unroll
    for (int c = 0; c < 16; ++c) {
      float xv[4];
      *(float4*)xv = *(float4*)&xs[cc + c][pg * 4];
      float wv[12];
      *(float4*)&wv[0] = *(float4*)&wch[c][og * 12 + 0];
      *(float4*)&wv[4] = *(float4*)&wch[c][og * 12 + 4];
      *(float4*)&wv[8] = *(float4*)&wch[c][og * 12 + 8];
#pragma unroll
      for (int i = 0; i < 12; ++i)
#pragma unroll
        for (int j = 0; j < 4; ++j) acc[i][j] = fmaf(wv[i], xv[j], acc[i][j]);
    }
  }
  __syncthreads();
#pragma unroll
  for (int i = 0; i < 12; ++i) {  // scatter accs: q rows -> xs, k/v rows -> kb
    const int o = og * 12 + i;
    const float4 v = make_float4(acc[i][0], acc[i][1], acc[i][2], acc[i][3]);
    if (o < 128) *(float4*)&xs[o][pg * 4] = v;
    else         *(float4*)&kb[o - 128][pg * 4] = v;
  }
  __syncthreads();
  // (a) q softmax over d, *scale, stage into d_out
  if (t < 128) {
    const int h = t >> 5, p = t & 31;
    float qv[32], m = -1e30f;
#pragma unroll
    for (int d = 0; d < 32; ++d) { qv[d] = xs[h * 32 + d][p]; m = fmaxf(m, qv[d]); }
    float s = 0.f;
#pragma unroll
    for (int d = 0; d < 32; ++d) { qv[d] = expf(qv[d] - m); s += qv[d]; }
    const float rs = SCALE / s;
    float* qo = q_out + ((size_t)b * 128 + h * 32) * NPIX + p0 + p;
#pragma unroll
    for (int d = 0; d < 32; ++d) qo[(size_t)d * NPIX] = qv[d] * rs;
  }
  // (b) exp(k) in place + row sums -> global atomic
  {
    const int r = t >> 1, ph = (t & 1) * 16;
    float s = 0.f;
#pragma unroll
    for (int i = 0; i < 16; ++i) {
      const float v = expf(kb[r][ph + i]);
      kb[r][ph + i] = v;
      s += v;
    }
    s += __shfl_xor(s, 1);
    if ((t & 1) == 0) atomicAdd(&sumexpG[b * 128 + r], s);
  }
  __syncthreads();
  // (c) partial context: ctx[h][d][e] += sum_p expk[h,d,p]*v[h,e,p]
  {
    const int h = t >> 6, d = (t & 63) >> 1, e0 = (t & 1) * 16;
    float ek[32];
#pragma unroll
    for (int p4 = 0; p4 < 8; ++p4)
      *(float4*)&ek[p4 * 4] = *(float4*)&kb[h * 32 + d][p4 * 4];
    for (int ei = 0; ei < 16; ++ei) {
      const int e = e0 + ei;
      const float* vr = &kb[128 + h * 32 + e][0];
      float s = 0.f;
#pragma unroll
      for (int p4 = 0; p4 < 8; ++p4) {
        const float4 vv = *(const float4*)&vr[p4 * 4];
        s = fmaf(ek[p4 * 4 + 0], vv.x, s);
        s = fmaf(ek[p4 * 4 + 1], vv.y, s);
        s = fmaf(ek[p4 * 4 + 2], vv.z, s);
        s = fmaf(ek[p4 * 4 + 3], vv.w, s);
      }
      atomicAdd(&ctxG[((size_t)b * 128 + h * 32 + d) * 32 + e], s);
    }
  }
}

// Fused: ctx-normalize + out = ctx^T q + out-proj + bias + rmsnorm.
// Reads q tile from io (d_out) and overwrites the same tile with the result.
__global__ __launch_bounds__(256, 2) void k3(
    const float* __restrict__ ctxG, const float* __restrict__ sumexpG,
    const float* __restrict__ out_w, const float* __restrict__ out_b,
    const float* __restrict__ out_norm_g, float* __restrict__ io) {
  __shared__ float cl[128][36];  // normalized ctx: row h*32+d, col e
  __shared__ float qs[128][36];  // q tile; reused as rmsnorm scratch
  __shared__ float o1[128][36];  // attention output channels
  __shared__ float wch[16][128];
  __shared__ float inv[32];

  const int t = threadIdx.x;
  const int b = blockIdx.y;
  const int p0 = blockIdx.x * 32;

  {  // load + normalize context
    const int r = t >> 1, e0 = (t & 1) * 16;
    const float ise = 1.f / sumexpG[b * 128 + r];
#pragma unroll
    for (int e4 = 0; e4 < 16; e4 += 4) {
      float4 v = *(const float4*)(ctxG + ((size_t)b * 128 + r) * 32 + e0 + e4);
      v.x *= ise; v.y *= ise; v.z *= ise; v.w *= ise;
      *(float4*)&cl[r][e0 + e4] = v;
    }
  }
  {  // load q tile
    const float* qb = io + (size_t)b * 128 * NPIX + p0;
    const int r = t >> 3, c4 = (t & 7) * 4;
#pragma unroll
    for (int pass = 0; pass < 4; ++pass) {
      const int row = pass * 32 + r;
      *(float4*)&qs[row][c4] = *(const float4*)(qb + (size_t)row * NPIX + c4);
    }
  }
  __syncthreads();
  const int rg = t >> 3, pg = t & 7;
  {  // o1[h*32+e][p] = sum_d cl[h*32+d][e] * qs[h*32+d][p]
    const int h = rg >> 3, e0 = (rg & 7) * 4;
    float a[4][4];
#pragma unroll
    for (int i = 0; i < 4; ++i)
#pragma unroll
      for (int j = 0; j < 4; ++j) a[i][j] = 0.f;
#pragma unroll
    for (int d = 0; d < 32; ++d) {
      float qv[4], cw[4];
      *(float4*)qv = *(float4*)&qs[h * 32 + d][pg * 4];
      *(float4*)cw = *(float4*)&cl[h * 32 + d][e0];
#pragma unroll
      for (int i = 0; i < 4; ++i)
#pragma unroll
        for (int j = 0; j < 4; ++j) a[i][j] = fmaf(cw[i], qv[j], a[i][j]);
    }
#pragma unroll
    for (int i = 0; i < 4; ++i)
      *(float4*)&o1[h * 32 + e0 + i][pg * 4] =
          make_float4(a[i][0], a[i][1], a[i][2], a[i][3]);
  }
  // out-proj: y[o][p] = out_b[o] + sum_c out_w[o][c]*o1[c][p]
  float y[4][4];
#pragma unroll
  for (int i = 0; i < 4; ++i) {
    const float bb = out_b[rg * 4 + i];
#pragma unroll
    for (int j = 0; j < 4; ++j) y[i][j] = bb;
  }
  for (int cc = 0; cc < 128; cc += 16) {
    __syncthreads();  // first iter also publishes o1
    for (int g = t; g < 512; g += 256) {
      const int o = g >> 2, ci = (g & 3) * 4;
      const float4 w = *(const float4*)(out_w + o * 128 + cc + ci);
      wch[ci + 0][o] = w.x; wch[ci + 1][o] = w.y;
      wch[ci + 2][o] = w.z; wch[ci + 3][o] = w.w;
    }
    __syncthreads();
#pragma unroll
    for (int c = 0; c < 16; ++c) {
      float wv[4], ov[4];
      *(float4*)wv = *(float4*)&wch[c][rg * 4];
      *(float4*)ov = *(float4*)&o1[cc + c][pg * 4];
#pragma unroll
      for (int i = 0; i < 4; ++i)
#pragma unroll
        for (int j = 0; j < 4; ++j) y[i][j] = fmaf(wv[i], ov[j], y[i][j]);
    }
  }
  __syncthreads();
#pragma unroll
  for (int j = 0; j < 4; ++j) {  // per-pixel sumsq partials into qs scratch
    float s = 0.f;
#pragma unroll
    for (int i = 0; i < 4; ++i) s = fmaf(y[i][j], y[i][j], s);
    qs[rg][pg * 4 + j] = s;
  }
  __syncthreads();
  if (t < 32) {
    float s = 0.f;
#pragma unroll
    for (int g = 0; g < 32; ++g) s += qs[g][t];
    inv[t] = SQRT128 / fmaxf(sqrtf(s), 1e-12f);
  }
  __syncthreads();
  {
    float* ob = io + (size_t)b * 128 * NPIX + p0;
#pragma unroll
    for (int i = 0; i < 4; ++i) {
      const int o = rg * 4 + i;
      const float g = out_norm_g[o];
      const float4 v = make_float4(y[i][0] * inv[pg * 4 + 0] * g,
                                   y[i][1] * inv[pg * 4 + 1] * g,
                                   y[i][2] * inv[pg * 4 + 2] * g,
                                   y[i][3] * inv[pg * 4 + 3] * g);
      *(float4*)(ob + (size_t)o * NPIX + pg * 4) = v;
    }
  }
}

extern "C" void kernel_launch(void* const* d_in, const int* in_sizes, int n_in,
                              void* d_out, int out_size, void* d_ws, size_t ws_size,
                              hipStream_t stream) {
  const float* x          = (const float*)d_in[0];
  const float* norm_g     = (const float*)d_in[1];
  const float* qkv_w      = (const float*)d_in[2];
  const float* mem_kv     = (const float*)d_in[3];
  const float* out_w      = (const float*)d_in[4];
  const float* out_b      = (const float*)d_in[5];
  const float* out_norm_g = (const float*)d_in[6];
  float* out = (float*)d_out;
  float* ctxG = (float*)d_ws;             // 64*32*32 floats
  float* sumexpG = ctxG + 64 * 32 * 32;   // 64*32 floats

  k_init<<<64, 256, 0, stream>>>(mem_kv, ctxG, sumexpG);
  k1<<<dim3(288, 16), 256, 0, stream>>>(x, norm_g, qkv_w, out, ctxG, sumexpG);
  k3<<<dim3(288, 16), 256, 0, stream>>>(ctxG, sumexpG, out_w, out_b, out_norm_g, out);
}

// Round 2
// 490.944 us; speedup vs baseline: 2.4916x; 2.4916x over previous
//
#include <hip/hip_runtime.h>
#include <math.h>

#define NPIX 9216
#define SCALE 0.17677669529663687f   // 32^-0.5
#define SQRT128 11.313708498984761f

// partials ws layout (floats):
//   part_ctx [16][32][4096] @ 0          (2,097,152)
//   part_se  [16][32][128]  @ 2097152    (65,536)
//   ctxG     [16][128][32]  @ 2162688    (65,536)
//   seG      [16][128]      @ 2228224    (2,048)

__global__ __launch_bounds__(256) void k_init(const float* __restrict__ mem_kv,
                                              float* __restrict__ ctxG,
                                              float* __restrict__ sumexpG) {
  const int bh = blockIdx.x;           // 0..63  (b*4+h)
  const int h = bh & 3;
  const float* mk = mem_kv + h * 128;        // mem_kv[0][h][d][j]
  const float* mv = mem_kv + 512 + h * 128;  // mem_kv[1][h][e][j]
  const int t = threadIdx.x;
  const int d = t >> 3, e0 = (t & 7) * 4;
  float ek[4], se = 0.f;
#pragma unroll
  for (int j = 0; j < 4; ++j) { ek[j] = expf(mk[d * 4 + j]); se += ek[j]; }
#pragma unroll
  for (int ei = 0; ei < 4; ++ei) {
    const int e = e0 + ei;
    float s = 0.f;
#pragma unroll
    for (int j = 0; j < 4; ++j) s += ek[j] * mv[e * 4 + j];
    ctxG[(bh * 32 + d) * 32 + e] = s;   // WRITE (re-init every launch)
  }
  if ((t & 7) == 0) sumexpG[bh * 32 + d] = se;
}

// Fused: rmsnorm + QKV GEMM + q-softmax (-> d_out staging) + exp(k)v^T partial ctx.
// Each block owns 9 tiles of 32 pixels (288 px), accumulates ctx/sumexp partials
// in registers, and emits ONE partial (PART) or one atomic burst (fallback).
template <bool PART>
__global__ __launch_bounds__(256, 2) void k1(
    const float* __restrict__ x, const float* __restrict__ norm_g,
    const float* __restrict__ qkv_w, float* __restrict__ q_out,
    float* __restrict__ ctx_dst, float* __restrict__ se_dst) {
  __shared__ float xs[128][36];   // x tile -> xn -> (reused) q tile
  __shared__ float kb[256][36];   // k rows 0..127 (->exp), v rows 128..255
  __shared__ float wch[16][384];  // transposed W chunk: wch[c][o]
  __shared__ float redu[8][32];
  __shared__ float inv[32];

  const int t = threadIdx.x;
  const int b = blockIdx.y;
  const int blk = blockIdx.x;     // 0..31
  const int og = t >> 3, pg = t & 7;
  const int ch = t >> 6, cd = (t & 63) >> 1, ce0 = (t & 1) * 16;

  float ctx_acc[16];
#pragma unroll
  for (int i = 0; i < 16; ++i) ctx_acc[i] = 0.f;
  float se_acc = 0.f;

  for (int it = 0; it < 9; ++it) {
    const int p0 = (blk * 9 + it) * 32;
    const float* xb = x + ((size_t)b * 128) * NPIX + p0;

    __syncthreads();  // prior tile's phase-a (xs) / phase-c (kb) reads done
    {  // load x tile (128 rows x 32 pixels)
      const int r = t >> 3, c4 = (t & 7) * 4;
#pragma unroll
      for (int pass = 0; pass < 4; ++pass) {
        const int row = pass * 32 + r;
        *(float4*)&xs[row][c4] = *(const float4*)(xb + (size_t)row * NPIX + c4);
      }
    }
    __syncthreads();
    {  // per-pixel sum of squares (partial)
      const int p = t & 31, g = t >> 5;
      float s = 0.f;
#pragma unroll
      for (int i = 0; i < 16; ++i) { const float v = xs[g * 16 + i][p]; s = fmaf(v, v, s); }
      redu[g][p] = s;
    }
    __syncthreads();
    if (t < 32) {
      float s = 0.f;
#pragma unroll
      for (int g = 0; g < 8; ++g) s += redu[g][t];
      inv[t] = SQRT128 / fmaxf(sqrtf(s), 1e-12f);
    }
    __syncthreads();
    {  // xn = x * inv[p] * norm_g[c]
      const int r = t >> 3, c4 = (t & 7) * 4;
#pragma unroll
      for (int pass = 0; pass < 4; ++pass) {
        const int row = pass * 32 + r;
        const float g = norm_g[row];
        float4 v = *(float4*)&xs[row][c4];
        v.x *= inv[c4] * g; v.y *= inv[c4 + 1] * g;
        v.z *= inv[c4 + 2] * g; v.w *= inv[c4 + 3] * g;
        *(float4*)&xs[row][c4] = v;
      }
    }
    // QKV GEMM: thread (og,pg) -> outputs o=og*12..+11, pixels p=pg*4..+3
    float acc[12][4];
#pragma unroll
    for (int i = 0; i < 12; ++i)
#pragma unroll
      for (int j = 0; j < 4; ++j) acc[i][j] = 0.f;

    for (int cc = 0; cc < 128; cc += 16) {
      __syncthreads();  // also covers xn-scale visibility on first chunk
      for (int g = t; g < 1536; g += 256) {  // stage W chunk, transposed
        const int o = g >> 2, ci = (g & 3) * 4;
        const float4 w = *(const float4*)(qkv_w + o * 128 + cc + ci);
        wch[ci + 0][o] = w.x; wch[ci + 1][o] = w.y;
        wch[ci + 2][o] = w.z; wch[ci + 3][o] = w.w;
      }
      __syncthreads();
#pragma unroll
      for (int c = 0; c < 16; ++c) {
        float xv[4];
        *(float4*)xv = *(float4*)&xs[cc + c][pg * 4];
        float wv[12];
        *(float4*)&wv[0] = *(float4*)&wch[c][og * 12 + 0];
        *(float4*)&wv[4] = *(float4*)&wch[c][og * 12 + 4];
        *(float4*)&wv[8] = *(float4*)&wch[c][og * 12 + 8];
#pragma unroll
        for (int i = 0; i < 12; ++i)
#pragma unroll
          for (int j = 0; j < 4; ++j) acc[i][j] = fmaf(wv[i], xv[j], acc[i][j]);
      }
    }
    __syncthreads();
#pragma unroll
    for (int i = 0; i < 12; ++i) {  // scatter: q rows -> xs, k/v rows -> kb
      const int o = og * 12 + i;
      const float4 v = make_float4(acc[i][0], acc[i][1], acc[i][2], acc[i][3]);
      if (o < 128) *(float4*)&xs[o][pg * 4] = v;
      else         *(float4*)&kb[o - 128][pg * 4] = v;
    }
    __syncthreads();
    // (a) q softmax over d, *scale, stage into d_out
    if (t < 128) {
      const int h = t >> 5, p = t & 31;
      float qv[32], m = -1e30f;
#pragma unroll
      for (int d = 0; d < 32; ++d) { qv[d] = xs[h * 32 + d][p]; m = fmaxf(m, qv[d]); }
      float s = 0.f;
#pragma unroll
      for (int d = 0; d < 32; ++d) { qv[d] = expf(qv[d] - m); s += qv[d]; }
      const float rs = SCALE / s;
      float* qo = q_out + ((size_t)b * 128 + h * 32) * NPIX + p0 + p;
#pragma unroll
      for (int d = 0; d < 32; ++d) qo[(size_t)d * NPIX] = qv[d] * rs;
    }
    // (b) exp(k) in place + row-sum into register accumulator
    {
      const int r = t >> 1, ph = (t & 1) * 16;
      float s = 0.f;
#pragma unroll
      for (int i = 0; i < 16; ++i) {
        const float v = expf(kb[r][ph + i]);
        kb[r][ph + i] = v;
        s += v;
      }
      se_acc += s;
    }
    __syncthreads();
    // (c) partial context: ctx_acc[e] += sum_p expk[h,d,p]*v[h,e,p]
    {
      float ekr[32];
#pragma unroll
      for (int p4 = 0; p4 < 8; ++p4)
        *(float4*)&ekr[p4 * 4] = *(float4*)&kb[ch * 32 + cd][p4 * 4];
#pragma unroll
      for (int ei = 0; ei < 16; ++ei) {
        const float* vr = &kb[128 + ch * 32 + ce0 + ei][0];
        float s = 0.f;
#pragma unroll
        for (int p4 = 0; p4 < 8; ++p4) {
          const float4 vv = *(const float4*)&vr[p4 * 4];
          s = fmaf(ekr[p4 * 4 + 0], vv.x, s);
          s = fmaf(ekr[p4 * 4 + 1], vv.y, s);
          s = fmaf(ekr[p4 * 4 + 2], vv.z, s);
          s = fmaf(ekr[p4 * 4 + 3], vv.w, s);
        }
        ctx_acc[ei] += s;
      }
    }
  }

  // epilogue: emit block's partial
  se_acc += __shfl_xor(se_acc, 1);
  if (PART) {
    float* dst = ctx_dst + ((size_t)(b * 32 + blk)) * 4096 + ch * 1024 + cd * 32 + ce0;
#pragma unroll
    for (int i4 = 0; i4 < 4; ++i4)
      *(float4*)(dst + i4 * 4) = make_float4(ctx_acc[i4 * 4 + 0], ctx_acc[i4 * 4 + 1],
                                             ctx_acc[i4 * 4 + 2], ctx_acc[i4 * 4 + 3]);
    if (!(t & 1)) se_dst[(b * 32 + blk) * 128 + (t >> 1)] = se_acc;
  } else {
#pragma unroll
    for (int i = 0; i < 16; ++i)
      atomicAdd(&ctx_dst[((size_t)b * 128 + ch * 32 + cd) * 32 + ce0 + i], ctx_acc[i]);
    if (!(t & 1)) atomicAdd(&se_dst[b * 128 + (t >> 1)], se_acc);
  }
}

// Reduce 32 partials per batch + mem_kv init contribution -> final ctx, sumexp
__global__ __launch_bounds__(256) void k_reduce(
    const float* __restrict__ part_ctx, const float* __restrict__ part_se,
    const float* __restrict__ mem_kv,
    float* __restrict__ ctxG, float* __restrict__ seG) {
  const int b = blockIdx.x;
  const int t = threadIdx.x;
  const int h = t >> 6, d = (t >> 1) & 31, e0 = (t & 1) * 16;

  // init from mem_kv (4 memory slots)
  const float* mk = mem_kv + h * 128 + d * 4;
  const float* mv = mem_kv + 512 + h * 128;
  float ek[4];
  float se0 = 0.f;
#pragma unroll
  for (int j = 0; j < 4; ++j) { ek[j] = expf(mk[j]); se0 += ek[j]; }
  float acc[16];
#pragma unroll
  for (int i = 0; i < 16; ++i) {
    const int e = e0 + i;
    float s = 0.f;
#pragma unroll
    for (int j = 0; j < 4; ++j) s += ek[j] * mv[e * 4 + j];
    acc[i] = s;
  }
  // sum the 32 block partials
  const float* src = part_ctx + (size_t)b * 32 * 4096 + t * 16;
  for (int p = 0; p < 32; ++p) {
#pragma unroll
    for (int i4 = 0; i4 < 4; ++i4) {
      const float4 v = *(const float4*)(src + (size_t)p * 4096 + i4 * 4);
      acc[i4 * 4 + 0] += v.x; acc[i4 * 4 + 1] += v.y;
      acc[i4 * 4 + 2] += v.z; acc[i4 * 4 + 3] += v.w;
    }
  }
  float* dst = ctxG + ((size_t)b * 128 + h * 32 + d) * 32 + e0;
#pragma unroll
  for (int i4 = 0; i4 < 4; ++i4)
    *(float4*)(dst + i4 * 4) = make_float4(acc[i4 * 4 + 0], acc[i4 * 4 + 1],
                                           acc[i4 * 4 + 2], acc[i4 * 4 + 3]);
  if (!(t & 1)) {
    const int r = t >> 1;   // == h*32+d
    float s = se0;
    for (int p = 0; p < 32; ++p) s += part_se[(size_t)b * 32 * 128 + p * 128 + r];
    seG[b * 128 + r] = s;
  }
}

// Fused: ctx-normalize + out = ctx^T q + out-proj + bias + rmsnorm.
// Reads q tile from io (d_out) and overwrites the same tile with the result.
__global__ __launch_bounds__(256, 2) void k3(
    const float* __restrict__ ctxG, const float* __restrict__ sumexpG,
    const float* __restrict__ out_w, const float* __restrict__ out_b,
    const float* __restrict__ out_norm_g, float* __restrict__ io) {
  __shared__ float cl[128][36];  // normalized ctx: row h*32+d, col e
  __shared__ float qs[128][36];  // q tile; reused as rmsnorm scratch
  __shared__ float o1[128][36];  // attention output channels
  __shared__ float wch[16][128];
  __shared__ float inv[32];

  const int t = threadIdx.x;
  const int b = blockIdx.y;
  const int p0 = blockIdx.x * 32;

  {  // load + normalize context
    const int r = t >> 1, e0 = (t & 1) * 16;
    const float ise = 1.f / sumexpG[b * 128 + r];
#pragma unroll
    for (int e4 = 0; e4 < 16; e4 += 4) {
      float4 v = *(const float4*)(ctxG + ((size_t)b * 128 + r) * 32 + e0 + e4);
      v.x *= ise; v.y *= ise; v.z *= ise; v.w *= ise;
      *(float4*)&cl[r][e0 + e4] = v;
    }
  }
  {  // load q tile
    const float* qb = io + (size_t)b * 128 * NPIX + p0;
    const int r = t >> 3, c4 = (t & 7) * 4;
#pragma unroll
    for (int pass = 0; pass < 4; ++pass) {
      const int row = pass * 32 + r;
      *(float4*)&qs[row][c4] = *(const float4*)(qb + (size_t)row * NPIX + c4);
    }
  }
  __syncthreads();
  const int rg = t >> 3, pg = t & 7;
  {  // o1[h*32+e][p] = sum_d cl[h*32+d][e] * qs[h*32+d][p]
    const int h = rg >> 3, e0 = (rg & 7) * 4;
    float a[4][4];
#pragma unroll
    for (int i = 0; i < 4; ++i)
#pragma unroll
      for (int j = 0; j < 4; ++j) a[i][j] = 0.f;
#pragma unroll
    for (int d = 0; d < 32; ++d) {
      float qv[4], cw[4];
      *(float4*)qv = *(float4*)&qs[h * 32 + d][pg * 4];
      *(float4*)cw = *(float4*)&cl[h * 32 + d][e0];
#pragma unroll
      for (int i = 0; i < 4; ++i)
#pragma unroll
        for (int j = 0; j < 4; ++j) a[i][j] = fmaf(cw[i], qv[j], a[i][j]);
    }
#pragma unroll
    for (int i = 0; i < 4; ++i)
      *(float4*)&o1[h * 32 + e0 + i][pg * 4] =
          make_float4(a[i][0], a[i][1], a[i][2], a[i][3]);
  }
  // out-proj: y[o][p] = out_b[o] + sum_c out_w[o][c]*o1[c][p]
  float y[4][4];
#pragma unroll
  for (int i = 0; i < 4; ++i) {
    const float bb = out_b[rg * 4 + i];
#pragma unroll
    for (int j = 0; j < 4; ++j) y[i][j] = bb;
  }
  for (int cc = 0; cc < 128; cc += 16) {
    __syncthreads();  // first iter also publishes o1
    for (int g = t; g < 512; g += 256) {
      const int o = g >> 2, ci = (g & 3) * 4;
      const float4 w = *(const float4*)(out_w + o * 128 + cc + ci);
      wch[ci + 0][o] = w.x; wch[ci + 1][o] = w.y;
      wch[ci + 2][o] = w.z; wch[ci + 3][o] = w.w;
    }
    __syncthreads();
#pragma unroll
    for (int c = 0; c < 16; ++c) {
      float wv[4], ov[4];
      *(float4*)wv = *(float4*)&wch[c][rg * 4];
      *(float4*)ov = *(float4*)&o1[cc + c][pg * 4];
#pragma unroll
      for (int i = 0; i < 4; ++i)
#pragma unroll
        for (int j = 0; j < 4; ++j) y[i][j] = fmaf(wv[i], ov[j], y[i][j]);
    }
  }
  __syncthreads();
#pragma unroll
  for (int j = 0; j < 4; ++j) {  // per-pixel sumsq partials into qs scratch
    float s = 0.f;
#pragma unroll
    for (int i = 0; i < 4; ++i) s = fmaf(y[i][j], y[i][j], s);
    qs[rg][pg * 4 + j] = s;
  }
  __syncthreads();
  if (t < 32) {
    float s = 0.f;
#pragma unroll
    for (int g = 0; g < 32; ++g) s += qs[g][t];
    inv[t] = SQRT128 / fmaxf(sqrtf(s), 1e-12f);
  }
  __syncthreads();
  {
    float* ob = io + (size_t)b * 128 * NPIX + p0;
#pragma unroll
    for (int i = 0; i < 4; ++i) {
      const int o = rg * 4 + i;
      const float g = out_norm_g[o];
      const float4 v = make_float4(y[i][0] * inv[pg * 4 + 0] * g,
                                   y[i][1] * inv[pg * 4 + 1] * g,
                                   y[i][2] * inv[pg * 4 + 2] * g,
                                   y[i][3] * inv[pg * 4 + 3] * g);
      *(float4*)(ob + (size_t)o * NPIX + pg * 4) = v;
    }
  }
}

extern "C" void kernel_launch(void* const* d_in, const int* in_sizes, int n_in,
                              void* d_out, int out_size, void* d_ws, size_t ws_size,
                              hipStream_t stream) {
  const float* x          = (const float*)d_in[0];
  const float* norm_g     = (const float*)d_in[1];
  const float* qkv_w      = (const float*)d_in[2];
  const float* mem_kv     = (const float*)d_in[3];
  const float* out_w      = (const float*)d_in[4];
  const float* out_b      = (const float*)d_in[5];
  const float* out_norm_g = (const float*)d_in[6];
  float* out = (float*)d_out;

  const size_t need = (size_t)(2097152 + 65536 + 65536 + 2048) * 4;
  if (ws_size >= need) {
    float* part_ctx = (float*)d_ws;
    float* part_se  = part_ctx + 2097152;
    float* ctxG     = part_se + 65536;
    float* seG      = ctxG + 65536;
    k1<true><<<dim3(32, 16), 256, 0, stream>>>(x, norm_g, qkv_w, out, part_ctx, part_se);
    k_reduce<<<16, 256, 0, stream>>>(part_ctx, part_se, mem_kv, ctxG, seG);
    k3<<<dim3(288, 16), 256, 0, stream>>>(ctxG, seG, out_w, out_b, out_norm_g, out);
  } else {
    float* ctxG = (float*)d_ws;
    float* seG  = ctxG + 65536;
    k_init<<<64, 256, 0, stream>>>(mem_kv, ctxG, seG);
    k1<false><<<dim3(32, 16), 256, 0, stream>>>(x, norm_g, qkv_w, out, ctxG, seG);
    k3<<<dim3(288, 16), 256, 0, stream>>>(ctxG, seG, out_w, out_b, out_norm_g, out);
  }
}

// Round 3
// 200.063 us; speedup vs baseline: 6.1144x; 2.4540x over previous
//
#include <hip/hip_runtime.h>
#include <math.h>

#define NPIX 9216
#define SCALE 0.17677669529663687f   // 32^-0.5
#define SQRT128 11.313708498984761f

typedef __attribute__((ext_vector_type(8))) short short8;
typedef __attribute__((ext_vector_type(4))) float f32x4;

static __device__ __forceinline__ unsigned short f2bf(float f) {
  union { float f; unsigned u; } v; v.f = f;
  return (unsigned short)((v.u + 0x7fffu + ((v.u >> 16) & 1u)) >> 16);
}
static __device__ __forceinline__ float bf2f(unsigned short h) {
  union { unsigned u; float f; } v; v.u = ((unsigned)h) << 16;
  return v.f;
}

// ws layout (f32 units), PART path:
//   part_ctx [16][32][4096] @ 0
//   part_se  [16][32][128]  @ 2097152
//   ctxG     [16][128][32]  @ 2162688
//   seG      [16][128]      @ 2228224
//   wbf      bf16[384][128] @ 2230272 (24576 f32 slots)

__global__ __launch_bounds__(256) void k_prep(const float* __restrict__ w,
                                              unsigned short* __restrict__ wb, int n) {
  const int i = blockIdx.x * 256 + threadIdx.x;
  if (i * 4 < n) {
    const float4 v = *(const float4*)(w + i * 4);
    unsigned long long p = (unsigned long long)f2bf(v.x)
                         | ((unsigned long long)f2bf(v.y) << 16)
                         | ((unsigned long long)f2bf(v.z) << 32)
                         | ((unsigned long long)f2bf(v.w) << 48);
    *(unsigned long long*)(wb + i * 4) = p;
  }
}

__global__ __launch_bounds__(256) void k_init(const float* __restrict__ mem_kv,
                                              float* __restrict__ ctxG,
                                              float* __restrict__ sumexpG) {
  const int bh = blockIdx.x;
  const int h = bh & 3;
  const float* mk = mem_kv + h * 128;
  const float* mv = mem_kv + 512 + h * 128;
  const int t = threadIdx.x;
  const int d = t >> 3, e0 = (t & 7) * 4;
  float ek[4], se = 0.f;
#pragma unroll
  for (int j = 0; j < 4; ++j) { ek[j] = expf(mk[d * 4 + j]); se += ek[j]; }
#pragma unroll
  for (int ei = 0; ei < 4; ++ei) {
    const int e = e0 + ei;
    float s = 0.f;
#pragma unroll
    for (int j = 0; j < 4; ++j) s += ek[j] * mv[e * 4 + j];
    ctxG[(bh * 32 + d) * 32 + e] = s;
  }
  if ((t & 7) == 0) sumexpG[bh * 32 + d] = se;
}

// Fused MFMA k1: rmsnorm + QKV GEMM (bf16 MFMA) + q-softmax -> d_out staging
// + exp(k)v^T partial ctx (bf16 MFMA, accs persist across 9 px-tiles).
template <bool PART>
__global__ __launch_bounds__(256, 2) void k1(
    const float* __restrict__ x, const float* __restrict__ norm_g,
    const unsigned short* __restrict__ wbf, float* __restrict__ q_out,
    float* __restrict__ ctx_dst, float* __restrict__ se_dst) {
  // LDS union: region A = xs f32[128][36] (18432B) OR qkv bf16[384][40] (30720B)
  //            region B = xnT bf16[32][136] (8704B); redu f32[8][32]; inv f32[32]
  __shared__ __align__(16) unsigned char smem[30720 + 8704 + 1024 + 128];
  float* xs = (float*)smem;
  unsigned short* qkv = (unsigned short*)smem;
  unsigned short* xnT = (unsigned short*)(smem + 30720);
  float* redu = (float*)(smem + 30720 + 8704);
  float* inv = (float*)(smem + 30720 + 8704 + 1024);

  const int t = threadIdx.x;
  const int b = blockIdx.y;
  const int blk = blockIdx.x;          // 0..31
  const int wv = t >> 6;               // wave 0..3 (also = head for ctx phase)
  const int lane = t & 63;
  const int lr = lane & 15;            // row/col within 16-tile
  const int lg = lane >> 4;            // k-group / row-group

  f32x4 acc[6][2];                     // QKV frags: wave rows [96*wv, +96)
  f32x4 ctx[2][2];                     // ctx accumulators (persist all 9 tiles)
#pragma unroll
  for (int i = 0; i < 6; ++i)
#pragma unroll
    for (int j = 0; j < 2; ++j)
#pragma unroll
      for (int r = 0; r < 4; ++r) acc[i][j][r] = 0.f;
#pragma unroll
  for (int i = 0; i < 2; ++i)
#pragma unroll
    for (int j = 0; j < 2; ++j)
#pragma unroll
      for (int r = 0; r < 4; ++r) ctx[i][j][r] = 0.f;
  float se_acc = 0.f;

  for (int it = 0; it < 9; ++it) {
    const int p0 = (blk * 9 + it) * 32;
    const float* xb = x + ((size_t)b * 128) * NPIX + p0;

    __syncthreads();  // prev iter's qkv (region A) reads done before xs overwrite
    {  // phase 0: load x tile f32 [128 ch][32 px]
      const int r = t >> 3, c4 = (t & 7) * 4;
#pragma unroll
      for (int pass = 0; pass < 4; ++pass) {
        const int row = pass * 32 + r;
        *(float4*)&xs[row * 36 + c4] = *(const float4*)(xb + (size_t)row * NPIX + c4);
      }
    }
    __syncthreads();
    {  // phase 1: per-pixel sumsq partials
      const int p = t & 31, g = t >> 5;
      float s = 0.f;
#pragma unroll
      for (int i = 0; i < 16; ++i) { const float v = xs[(g * 16 + i) * 36 + p]; s = fmaf(v, v, s); }
      redu[g * 32 + p] = s;
    }
    __syncthreads();
    if (t < 32) {
      float s = 0.f;
#pragma unroll
      for (int g = 0; g < 8; ++g) s += redu[g * 32 + t];
      inv[t] = SQRT128 / fmaxf(sqrtf(s), 1e-12f);
    }
    __syncthreads();
    {  // phase 2: scale + cvt bf16 + transpose -> xnT[px][ch]
      const int r = t >> 3, c4 = (t & 7) * 4;
#pragma unroll
      for (int pass = 0; pass < 4; ++pass) {
        const int row = pass * 32 + r;
        const float g = norm_g[row];
        const float4 v = *(float4*)&xs[row * 36 + c4];
        xnT[(c4 + 0) * 136 + row] = f2bf(v.x * inv[c4 + 0] * g);
        xnT[(c4 + 1) * 136 + row] = f2bf(v.y * inv[c4 + 1] * g);
        xnT[(c4 + 2) * 136 + row] = f2bf(v.z * inv[c4 + 2] * g);
        xnT[(c4 + 3) * 136 + row] = f2bf(v.w * inv[c4 + 3] * g);
      }
    }
    __syncthreads();
    {  // phase 3: QKV MFMA. A = W[384][128] (global bf16), B = xnT
      short8 bfr[4][2];
#pragma unroll
      for (int ks = 0; ks < 4; ++ks)
#pragma unroll
        for (int nt = 0; nt < 2; ++nt)
          bfr[ks][nt] = *(const short8*)&xnT[(nt * 16 + lr) * 136 + ks * 32 + lg * 8];
      const unsigned short* wbase = wbf + (size_t)(96 * wv + lr) * 128 + lg * 8;
#pragma unroll
      for (int mt = 0; mt < 6; ++mt) {
#pragma unroll
        for (int ks = 0; ks < 4; ++ks) {
          const short8 af = *(const short8*)(wbase + mt * 16 * 128 + ks * 32);
          acc[mt][0] = __builtin_amdgcn_mfma_f32_16x16x32_bf16(af, bfr[ks][0], acc[mt][0], 0, 0, 0);
          acc[mt][1] = __builtin_amdgcn_mfma_f32_16x16x32_bf16(af, bfr[ks][1], acc[mt][1], 0, 0, 0);
        }
      }
    }
    // phase 4: D frags -> qkv bf16 [384][40] (region A; xs dead, xnT disjoint)
    {
#pragma unroll
      for (int mt = 0; mt < 6; ++mt)
#pragma unroll
        for (int nt = 0; nt < 2; ++nt)
#pragma unroll
          for (int r = 0; r < 4; ++r) {
            const int row = 96 * wv + mt * 16 + lg * 4 + r;
            qkv[row * 40 + nt * 16 + lr] = f2bf(acc[mt][nt][r]);
            acc[mt][nt][r] = 0.f;  // reset for next tile
          }
    }
    __syncthreads();
    // phase 5a: q softmax over d, *scale, stage into d_out ([b][ch][pix] layout)
    if (t < 128) {
      const int h = t >> 5, p = t & 31;
      float qv[32], m = -1e30f;
#pragma unroll
      for (int d = 0; d < 32; ++d) { qv[d] = bf2f(qkv[(h * 32 + d) * 40 + p]); m = fmaxf(m, qv[d]); }
      float s = 0.f;
#pragma unroll
      for (int d = 0; d < 32; ++d) { qv[d] = expf(qv[d] - m); s += qv[d]; }
      const float rs = SCALE / s;
      float* qo = q_out + ((size_t)b * 128 + h * 32) * NPIX + p0 + p;
#pragma unroll
      for (int d = 0; d < 32; ++d) qo[(size_t)d * NPIX] = qv[d] * rs;
    }
    // phase 5b: exp(k) in place (bf16) + row-sum accumulate
    {
      const int row = 128 + (t >> 1);
      const int ph = (t & 1) * 16;
      float s = 0.f;
#pragma unroll
      for (int i = 0; i < 16; ++i) {
        const float v = expf(bf2f(qkv[row * 40 + ph + i]));
        qkv[row * 40 + ph + i] = f2bf(v);
        s += v;
      }
      se_acc += s;
    }
    __syncthreads();
    // phase 6: ctx MFMA. head = wv. A = expk[d][px], B[k=px][n=e] = v[e][px]
    {
#pragma unroll
      for (int dt = 0; dt < 2; ++dt) {
        const short8 af = *(const short8*)&qkv[(128 + wv * 32 + dt * 16 + lr) * 40 + lg * 8];
#pragma unroll
        for (int et = 0; et < 2; ++et) {
          const short8 bf = *(const short8*)&qkv[(256 + wv * 32 + et * 16 + lr) * 40 + lg * 8];
          ctx[dt][et] = __builtin_amdgcn_mfma_f32_16x16x32_bf16(af, bf, ctx[dt][et], 0, 0, 0);
        }
      }
    }
  }

  // epilogue: se pair-reduce + ctx frag writes
  se_acc += __shfl_xor(se_acc, 1);
  if (PART) {
    float* dst = ctx_dst + ((size_t)(b * 32 + blk)) * 4096 + wv * 1024;
#pragma unroll
    for (int dt = 0; dt < 2; ++dt)
#pragma unroll
      for (int et = 0; et < 2; ++et)
#pragma unroll
        for (int r = 0; r < 4; ++r)
          dst[(dt * 16 + lg * 4 + r) * 32 + et * 16 + lr] = ctx[dt][et][r];
    if (!(t & 1)) se_dst[(b * 32 + blk) * 128 + (t >> 1)] = se_acc;
  } else {
#pragma unroll
    for (int dt = 0; dt < 2; ++dt)
#pragma unroll
      for (int et = 0; et < 2; ++et)
#pragma unroll
        for (int r = 0; r < 4; ++r)
          atomicAdd(&ctx_dst[((size_t)b * 128 + wv * 32 + dt * 16 + lg * 4 + r) * 32 + et * 16 + lr],
                    ctx[dt][et][r]);
    if (!(t & 1)) atomicAdd(&se_dst[b * 128 + (t >> 1)], se_acc);
  }
}

// Reduce 32 partials per batch + mem_kv init contribution -> final ctx, sumexp
__global__ __launch_bounds__(256) void k_reduce(
    const float* __restrict__ part_ctx, const float* __restrict__ part_se,
    const float* __restrict__ mem_kv,
    float* __restrict__ ctxG, float* __restrict__ seG) {
  const int b = blockIdx.x;
  const int t = threadIdx.x;
  const int h = t >> 6, d = (t >> 1) & 31, e0 = (t & 1) * 16;

  const float* mk = mem_kv + h * 128 + d * 4;
  const float* mv = mem_kv + 512 + h * 128;
  float ek[4];
  float se0 = 0.f;
#pragma unroll
  for (int j = 0; j < 4; ++j) { ek[j] = expf(mk[j]); se0 += ek[j]; }
  float acc[16];
#pragma unroll
  for (int i = 0; i < 16; ++i) {
    const int e = e0 + i;
    float s = 0.f;
#pragma unroll
    for (int j = 0; j < 4; ++j) s += ek[j] * mv[e * 4 + j];
    acc[i] = s;
  }
  const float* src = part_ctx + (size_t)b * 32 * 4096 + t * 16;
  for (int p = 0; p < 32; ++p) {
#pragma unroll
    for (int i4 = 0; i4 < 4; ++i4) {
      const float4 v = *(const float4*)(src + (size_t)p * 4096 + i4 * 4);
      acc[i4 * 4 + 0] += v.x; acc[i4 * 4 + 1] += v.y;
      acc[i4 * 4 + 2] += v.z; acc[i4 * 4 + 3] += v.w;
    }
  }
  float* dst = ctxG + ((size_t)b * 128 + h * 32 + d) * 32 + e0;
#pragma unroll
  for (int i4 = 0; i4 < 4; ++i4)
    *(float4*)(dst + i4 * 4) = make_float4(acc[i4 * 4 + 0], acc[i4 * 4 + 1],
                                           acc[i4 * 4 + 2], acc[i4 * 4 + 3]);
  if (!(t & 1)) {
    const int r = t >> 1;
    float s = se0;
    for (int p = 0; p < 32; ++p) s += part_se[(size_t)b * 32 * 128 + p * 128 + r];
    seG[b * 128 + r] = s;
  }
}

// Fused: ctx-normalize + out = ctx^T q + out-proj + bias + rmsnorm. (unchanged)
__global__ __launch_bounds__(256, 2) void k3(
    const float* __restrict__ ctxG, const float* __restrict__ sumexpG,
    const float* __restrict__ out_w, const float* __restrict__ out_b,
    const float* __restrict__ out_norm_g, float* __restrict__ io) {
  __shared__ float cl[128][36];
  __shared__ float qs[128][36];
  __shared__ float o1[128][36];
  __shared__ float wch[16][128];
  __shared__ float inv[32];

  const int t = threadIdx.x;
  const int b = blockIdx.y;
  const int p0 = blockIdx.x * 32;

  {
    const int r = t >> 1, e0 = (t & 1) * 16;
    const float ise = 1.f / sumexpG[b * 128 + r];
#pragma unroll
    for (int e4 = 0; e4 < 16; e4 += 4) {
      float4 v = *(const float4*)(ctxG + ((size_t)b * 128 + r) * 32 + e0 + e4);
      v.x *= ise; v.y *= ise; v.z *= ise; v.w *= ise;
      *(float4*)&cl[r][e0 + e4] = v;
    }
  }
  {
    const float* qb = io + (size_t)b * 128 * NPIX + p0;
    const int r = t >> 3, c4 = (t & 7) * 4;
#pragma unroll
    for (int pass = 0; pass < 4; ++pass) {
      const int row = pass * 32 + r;
      *(float4*)&qs[row][c4] = *(const float4*)(qb + (size_t)row * NPIX + c4);
    }
  }
  __syncthreads();
  const int rg = t >> 3, pg = t & 7;
  {
    const int h = rg >> 3, e0 = (rg & 7) * 4;
    float a[4][4];
#pragma unroll
    for (int i = 0; i < 4; ++i)
#pragma unroll
      for (int j = 0; j < 4; ++j) a[i][j] = 0.f;
#pragma unroll
    for (int d = 0; d < 32; ++d) {
      float qv[4], cw[4];
      *(float4*)qv = *(float4*)&qs[h * 32 + d][pg * 4];
      *(float4*)cw = *(float4*)&cl[h * 32 + d][e0];
#pragma unroll
      for (int i = 0; i < 4; ++i)
#pragma unroll
        for (int j = 0; j < 4; ++j) a[i][j] = fmaf(cw[i], qv[j], a[i][j]);
    }
#pragma unroll
    for (int i = 0; i < 4; ++i)
      *(float4*)&o1[h * 32 + e0 + i][pg * 4] =
          make_float4(a[i][0], a[i][1], a[i][2], a[i][3]);
  }
  float y[4][4];
#pragma unroll
  for (int i = 0; i < 4; ++i) {
    const float bb = out_b[rg * 4 + i];
#pragma unroll
    for (int j = 0; j < 4; ++j) y[i][j] = bb;
  }
  for (int cc = 0; cc < 128; cc += 16) {
    __syncthreads();
    for (int g = t; g < 512; g += 256) {
      const int o = g >> 2, ci = (g & 3) * 4;
      const float4 w = *(const float4*)(out_w + o * 128 + cc + ci);
      wch[ci + 0][o] = w.x; wch[ci + 1][o] = w.y;
      wch[ci + 2][o] = w.z; wch[ci + 3][o] = w.w;
    }
    __syncthreads();
#pragma unroll
    for (int c = 0; c < 16; ++c) {
      float wv[4], ov[4];
      *(float4*)wv = *(float4*)&wch[c][rg * 4];
      *(float4*)ov = *(float4*)&o1[cc + c][pg * 4];
#pragma unroll
      for (int i = 0; i < 4; ++i)
#pragma unroll
        for (int j = 0; j < 4; ++j) y[i][j] = fmaf(wv[i], ov[j], y[i][j]);
    }
  }
  __syncthreads();
#pragma unroll
  for (int j = 0; j < 4; ++j) {
    float s = 0.f;
#pragma unroll
    for (int i = 0; i < 4; ++i) s = fmaf(y[i][j], y[i][j], s);
    qs[rg][pg * 4 + j] = s;
  }
  __syncthreads();
  if (t < 32) {
    float s = 0.f;
#pragma unroll
    for (int g = 0; g < 32; ++g) s += qs[g][t];
    inv[t] = SQRT128 / fmaxf(sqrtf(s), 1e-12f);
  }
  __syncthreads();
  {
    float* ob = io + (size_t)b * 128 * NPIX + p0;
#pragma unroll
    for (int i = 0; i < 4; ++i) {
      const int o = rg * 4 + i;
      const float g = out_norm_g[o];
      const float4 v = make_float4(y[i][0] * inv[pg * 4 + 0] * g,
                                   y[i][1] * inv[pg * 4 + 1] * g,
                                   y[i][2] * inv[pg * 4 + 2] * g,
                                   y[i][3] * inv[pg * 4 + 3] * g);
      *(float4*)(ob + (size_t)o * NPIX + pg * 4) = v;
    }
  }
}

extern "C" void kernel_launch(void* const* d_in, const int* in_sizes, int n_in,
                              void* d_out, int out_size, void* d_ws, size_t ws_size,
                              hipStream_t stream) {
  const float* x          = (const float*)d_in[0];
  const float* norm_g     = (const float*)d_in[1];
  const float* qkv_w      = (const float*)d_in[2];
  const float* mem_kv     = (const float*)d_in[3];
  const float* out_w      = (const float*)d_in[4];
  const float* out_b      = (const float*)d_in[5];
  const float* out_norm_g = (const float*)d_in[6];
  float* out = (float*)d_out;

  const size_t need = (size_t)(2097152 + 65536 + 65536 + 2048 + 24576) * 4;
  if (ws_size >= need) {
    float* part_ctx = (float*)d_ws;
    float* part_se  = part_ctx + 2097152;
    float* ctxG     = part_se + 65536;
    float* seG      = ctxG + 65536;
    unsigned short* wbf = (unsigned short*)(seG + 2048);
    k_prep<<<48, 256, 0, stream>>>(qkv_w, wbf, 49152);
    k1<true><<<dim3(32, 16), 256, 0, stream>>>(x, norm_g, wbf, out, part_ctx, part_se);
    k_reduce<<<16, 256, 0, stream>>>(part_ctx, part_se, mem_kv, ctxG, seG);
    k3<<<dim3(288, 16), 256, 0, stream>>>(ctxG, seG, out_w, out_b, out_norm_g, out);
  } else {
    float* ctxG = (float*)d_ws;
    float* seG  = ctxG + 65536;
    unsigned short* wbf = (unsigned short*)(seG + 2048);
    k_prep<<<48, 256, 0, stream>>>(qkv_w, wbf, 49152);
    k_init<<<64, 256, 0, stream>>>(mem_kv, ctxG, seG);
    k1<false><<<dim3(32, 16), 256, 0, stream>>>(x, norm_g, wbf, out, ctxG, seG);
    k3<<<dim3(288, 16), 256, 0, stream>>>(ctxG, seG, out_w, out_b, out_norm_g, out);
  }
}

// Round 4
// 121.730 us; speedup vs baseline: 10.0490x; 1.6435x over previous
//
#include <hip/hip_runtime.h>
#include <math.h>

#define NPIX 9216
#define SCALE 0.17677669529663687f   // 32^-0.5
#define SQRT128 11.313708498984761f

typedef __attribute__((ext_vector_type(8))) short short8;
typedef __attribute__((ext_vector_type(4))) float f32x4;

static __device__ __forceinline__ unsigned short f2bf(float f) {
  union { float f; unsigned u; } v; v.f = f;
  return (unsigned short)((v.u + 0x7fffu + ((v.u >> 16) & 1u)) >> 16);
}
static __device__ __forceinline__ float bf2f(unsigned short h) {
  union { unsigned u; float f; } v; v.u = ((unsigned)h) << 16;
  return v.f;
}

// ws layout (f32 units), PART path:
//   part_ctx [16][32][4096] @ 0                       (2,097,152)
//   part_se  [16][32][128]  @ 2097152                 (65,536)
//   wbf  bf16[384][128]     @ 2162688                 (24,576 f32 slots)
//   owb  bf16[128][128]     @ 2187264                 (8,192 f32 slots)
//   ctxnT bf16[16][4][32][32] @ 2195456               (32,768 f32 slots)

__global__ __launch_bounds__(256) void k_prep(const float* __restrict__ w,
                                              unsigned short* __restrict__ wb, int n) {
  const int i = blockIdx.x * 256 + threadIdx.x;
  if (i * 4 < n) {
    const float4 v = *(const float4*)(w + i * 4);
    unsigned long long p = (unsigned long long)f2bf(v.x)
                         | ((unsigned long long)f2bf(v.y) << 16)
                         | ((unsigned long long)f2bf(v.z) << 32)
                         | ((unsigned long long)f2bf(v.w) << 48);
    *(unsigned long long*)(wb + i * 4) = p;
  }
}

__global__ __launch_bounds__(256) void k_init(const float* __restrict__ mem_kv,
                                              float* __restrict__ ctxG,
                                              float* __restrict__ sumexpG) {
  const int bh = blockIdx.x;
  const int h = bh & 3;
  const float* mk = mem_kv + h * 128;
  const float* mv = mem_kv + 512 + h * 128;
  const int t = threadIdx.x;
  const int d = t >> 3, e0 = (t & 7) * 4;
  float ek[4], se = 0.f;
#pragma unroll
  for (int j = 0; j < 4; ++j) { ek[j] = expf(mk[d * 4 + j]); se += ek[j]; }
#pragma unroll
  for (int ei = 0; ei < 4; ++ei) {
    const int e = e0 + ei;
    float s = 0.f;
#pragma unroll
    for (int j = 0; j < 4; ++j) s += ek[j] * mv[e * 4 + j];
    ctxG[(bh * 32 + d) * 32 + e] = s;
  }
  if ((t & 7) == 0) sumexpG[bh * 32 + d] = se;
}

// Fused MFMA k1: rmsnorm + QKV GEMM (bf16 MFMA) + q-softmax -> d_out staging
// + exp(k)v^T partial ctx (bf16 MFMA, accs persist across 9 px-tiles).
template <bool PART>
__global__ __launch_bounds__(256, 2) void k1(
    const float* __restrict__ x, const float* __restrict__ norm_g,
    const unsigned short* __restrict__ wbf, float* __restrict__ q_out,
    float* __restrict__ ctx_dst, float* __restrict__ se_dst) {
  __shared__ __align__(16) unsigned char smem[30720 + 8704 + 1024 + 128];
  float* xs = (float*)smem;
  unsigned short* qkv = (unsigned short*)smem;
  unsigned short* xnT = (unsigned short*)(smem + 30720);
  float* redu = (float*)(smem + 30720 + 8704);
  float* inv = (float*)(smem + 30720 + 8704 + 1024);

  const int t = threadIdx.x;
  const int b = blockIdx.y;
  const int blk = blockIdx.x;          // 0..31
  const int wv = t >> 6;               // wave 0..3 (also = head for ctx phase)
  const int lane = t & 63;
  const int lr = lane & 15;
  const int lg = lane >> 4;

  f32x4 acc[6][2];
  f32x4 ctx[2][2];
#pragma unroll
  for (int i = 0; i < 6; ++i)
#pragma unroll
    for (int j = 0; j < 2; ++j)
#pragma unroll
      for (int r = 0; r < 4; ++r) acc[i][j][r] = 0.f;
#pragma unroll
  for (int i = 0; i < 2; ++i)
#pragma unroll
    for (int j = 0; j < 2; ++j)
#pragma unroll
      for (int r = 0; r < 4; ++r) ctx[i][j][r] = 0.f;
  float se_acc = 0.f;

  for (int it = 0; it < 9; ++it) {
    const int p0 = (blk * 9 + it) * 32;
    const float* xb = x + ((size_t)b * 128) * NPIX + p0;

    __syncthreads();
    {  // phase 0: load x tile f32 [128 ch][32 px]
      const int r = t >> 3, c4 = (t & 7) * 4;
#pragma unroll
      for (int pass = 0; pass < 4; ++pass) {
        const int row = pass * 32 + r;
        *(float4*)&xs[row * 36 + c4] = *(const float4*)(xb + (size_t)row * NPIX + c4);
      }
    }
    __syncthreads();
    {  // phase 1: per-pixel sumsq partials
      const int p = t & 31, g = t >> 5;
      float s = 0.f;
#pragma unroll
      for (int i = 0; i < 16; ++i) { const float v = xs[(g * 16 + i) * 36 + p]; s = fmaf(v, v, s); }
      redu[g * 32 + p] = s;
    }
    __syncthreads();
    if (t < 32) {
      float s = 0.f;
#pragma unroll
      for (int g = 0; g < 8; ++g) s += redu[g * 32 + t];
      inv[t] = SQRT128 / fmaxf(sqrtf(s), 1e-12f);
    }
    __syncthreads();
    {  // phase 2: scale + cvt bf16 + transpose -> xnT[px][ch]
      const int r = t >> 3, c4 = (t & 7) * 4;
#pragma unroll
      for (int pass = 0; pass < 4; ++pass) {
        const int row = pass * 32 + r;
        const float g = norm_g[row];
        const float4 v = *(float4*)&xs[row * 36 + c4];
        xnT[(c4 + 0) * 136 + row] = f2bf(v.x * inv[c4 + 0] * g);
        xnT[(c4 + 1) * 136 + row] = f2bf(v.y * inv[c4 + 1] * g);
        xnT[(c4 + 2) * 136 + row] = f2bf(v.z * inv[c4 + 2] * g);
        xnT[(c4 + 3) * 136 + row] = f2bf(v.w * inv[c4 + 3] * g);
      }
    }
    __syncthreads();
    {  // phase 3: QKV MFMA
      short8 bfr[4][2];
#pragma unroll
      for (int ks = 0; ks < 4; ++ks)
#pragma unroll
        for (int nt = 0; nt < 2; ++nt)
          bfr[ks][nt] = *(const short8*)&xnT[(nt * 16 + lr) * 136 + ks * 32 + lg * 8];
      const unsigned short* wbase = wbf + (size_t)(96 * wv + lr) * 128 + lg * 8;
#pragma unroll
      for (int mt = 0; mt < 6; ++mt) {
#pragma unroll
        for (int ks = 0; ks < 4; ++ks) {
          const short8 af = *(const short8*)(wbase + mt * 16 * 128 + ks * 32);
          acc[mt][0] = __builtin_amdgcn_mfma_f32_16x16x32_bf16(af, bfr[ks][0], acc[mt][0], 0, 0, 0);
          acc[mt][1] = __builtin_amdgcn_mfma_f32_16x16x32_bf16(af, bfr[ks][1], acc[mt][1], 0, 0, 0);
        }
      }
    }
    {  // phase 4: D frags -> qkv bf16 [384][40]
#pragma unroll
      for (int mt = 0; mt < 6; ++mt)
#pragma unroll
        for (int nt = 0; nt < 2; ++nt)
#pragma unroll
          for (int r = 0; r < 4; ++r) {
            const int row = 96 * wv + mt * 16 + lg * 4 + r;
            qkv[row * 40 + nt * 16 + lr] = f2bf(acc[mt][nt][r]);
            acc[mt][nt][r] = 0.f;
          }
    }
    __syncthreads();
    // phase 5a: q softmax over d, *scale, stage into d_out
    if (t < 128) {
      const int h = t >> 5, p = t & 31;
      float qv[32], m = -1e30f;
#pragma unroll
      for (int d = 0; d < 32; ++d) { qv[d] = bf2f(qkv[(h * 32 + d) * 40 + p]); m = fmaxf(m, qv[d]); }
      float s = 0.f;
#pragma unroll
      for (int d = 0; d < 32; ++d) { qv[d] = expf(qv[d] - m); s += qv[d]; }
      const float rs = SCALE / s;
      float* qo = q_out + ((size_t)b * 128 + h * 32) * NPIX + p0 + p;
#pragma unroll
      for (int d = 0; d < 32; ++d) qo[(size_t)d * NPIX] = qv[d] * rs;
    }
    // phase 5b: exp(k) in place + row-sum accumulate
    {
      const int row = 128 + (t >> 1);
      const int ph = (t & 1) * 16;
      float s = 0.f;
#pragma unroll
      for (int i = 0; i < 16; ++i) {
        const float v = expf(bf2f(qkv[row * 40 + ph + i]));
        qkv[row * 40 + ph + i] = f2bf(v);
        s += v;
      }
      se_acc += s;
    }
    __syncthreads();
    // phase 6: ctx MFMA
    {
#pragma unroll
      for (int dt = 0; dt < 2; ++dt) {
        const short8 af = *(const short8*)&qkv[(128 + wv * 32 + dt * 16 + lr) * 40 + lg * 8];
#pragma unroll
        for (int et = 0; et < 2; ++et) {
          const short8 bf = *(const short8*)&qkv[(256 + wv * 32 + et * 16 + lr) * 40 + lg * 8];
          ctx[dt][et] = __builtin_amdgcn_mfma_f32_16x16x32_bf16(af, bf, ctx[dt][et], 0, 0, 0);
        }
      }
    }
  }

  se_acc += __shfl_xor(se_acc, 1);
  if (PART) {
    float* dst = ctx_dst + ((size_t)(b * 32 + blk)) * 4096 + wv * 1024;
#pragma unroll
    for (int dt = 0; dt < 2; ++dt)
#pragma unroll
      for (int et = 0; et < 2; ++et)
#pragma unroll
        for (int r = 0; r < 4; ++r)
          dst[(dt * 16 + lg * 4 + r) * 32 + et * 16 + lr] = ctx[dt][et][r];
    if (!(t & 1)) se_dst[(b * 32 + blk) * 128 + (t >> 1)] = se_acc;
  } else {
#pragma unroll
    for (int dt = 0; dt < 2; ++dt)
#pragma unroll
      for (int et = 0; et < 2; ++et)
#pragma unroll
        for (int r = 0; r < 4; ++r)
          atomicAdd(&ctx_dst[((size_t)b * 128 + wv * 32 + dt * 16 + lg * 4 + r) * 32 + et * 16 + lr],
                    ctx[dt][et][r]);
    if (!(t & 1)) atomicAdd(&se_dst[b * 128 + (t >> 1)], se_acc);
  }
}

// Reduce 32 partials + mem_kv -> normalized transposed bf16 ctx: ctxnT[b][h][e][d]
__global__ __launch_bounds__(256) void k_reduce(
    const float* __restrict__ part_ctx, const float* __restrict__ part_se,
    const float* __restrict__ mem_kv, unsigned short* __restrict__ ctxnT) {
  const int b = blockIdx.x;
  const int t = threadIdx.x;
  const int h = t >> 6, d = (t >> 1) & 31, e0 = (t & 1) * 16;

  const float* mk = mem_kv + h * 128 + d * 4;
  const float* mv = mem_kv + 512 + h * 128;
  float ek[4];
  float se = 0.f;
#pragma unroll
  for (int j = 0; j < 4; ++j) { ek[j] = expf(mk[j]); se += ek[j]; }
  float acc[16];
#pragma unroll
  for (int i = 0; i < 16; ++i) {
    const int e = e0 + i;
    float s = 0.f;
#pragma unroll
    for (int j = 0; j < 4; ++j) s += ek[j] * mv[e * 4 + j];
    acc[i] = s;
  }
  const float* src = part_ctx + (size_t)b * 32 * 4096 + t * 16;
  for (int p = 0; p < 32; ++p) {
#pragma unroll
    for (int i4 = 0; i4 < 4; ++i4) {
      const float4 v = *(const float4*)(src + (size_t)p * 4096 + i4 * 4);
      acc[i4 * 4 + 0] += v.x; acc[i4 * 4 + 1] += v.y;
      acc[i4 * 4 + 2] += v.z; acc[i4 * 4 + 3] += v.w;
    }
  }
  const int r = h * 32 + d;
  for (int p = 0; p < 32; ++p) se += part_se[(size_t)b * 32 * 128 + p * 128 + r];
  const float ise = 1.f / se;
  unsigned short* dst = ctxnT + ((size_t)(b * 4 + h) * 32) * 32;
#pragma unroll
  for (int i = 0; i < 16; ++i)
    dst[(e0 + i) * 32 + d] = f2bf(acc[i] * ise);
}

// Fallback-path normalizer: ctxG/seG (f32) -> ctxnT bf16
__global__ __launch_bounds__(256) void k_norm(
    const float* __restrict__ ctxG, const float* __restrict__ seG,
    unsigned short* __restrict__ ctxnT) {
  const int b = blockIdx.x;
  const int t = threadIdx.x;
  const int h = t >> 6, d = (t >> 1) & 31, e0 = (t & 1) * 16;
  const int r = h * 32 + d;
  const float ise = 1.f / seG[b * 128 + r];
  const float* src = ctxG + ((size_t)b * 128 + r) * 32;
  unsigned short* dst = ctxnT + ((size_t)(b * 4 + h) * 32) * 32;
#pragma unroll
  for (int i = 0; i < 16; ++i)
    dst[(e0 + i) * 32 + d] = f2bf(src[e0 + i] * ise);
}

// MFMA k3: q->bf16 transpose + (ctxn^T q) MFMA + out-proj MFMA + bias + rmsnorm
__global__ __launch_bounds__(256) void k3(
    const unsigned short* __restrict__ ctxnT, const unsigned short* __restrict__ owb,
    const float* __restrict__ out_b, const float* __restrict__ out_norm_g,
    float* __restrict__ io) {
  __shared__ __align__(16) unsigned char smem[8704 + 8704 + 2048 + 128];
  unsigned short* qT = (unsigned short*)smem;                 // [32 px][136 ch]
  unsigned short* o1T = (unsigned short*)(smem + 8704);       // [32 px][136 ch]
  float* redu = (float*)(smem + 8704 + 8704);                 // [16][32]
  float* inv = (float*)(smem + 8704 + 8704 + 2048);           // [32]

  const int t = threadIdx.x;
  const int b = blockIdx.y;
  const int p0 = blockIdx.x * 32;
  const int wv = t >> 6;               // wave = head (step1), row-quarter (step2)
  const int lane = t & 63;
  const int lr = lane & 15;
  const int lg = lane >> 4;

  {  // load q tile f32 [128 ch][32 px] -> qT bf16 [px][ch]
    const float* qb = io + (size_t)b * 128 * NPIX + p0;
    const int r = t >> 3, c4 = (t & 7) * 4;
#pragma unroll
    for (int pass = 0; pass < 4; ++pass) {
      const int row = pass * 32 + r;
      const float4 v = *(const float4*)(qb + (size_t)row * NPIX + c4);
      qT[(c4 + 0) * 136 + row] = f2bf(v.x);
      qT[(c4 + 1) * 136 + row] = f2bf(v.y);
      qT[(c4 + 2) * 136 + row] = f2bf(v.z);
      qT[(c4 + 3) * 136 + row] = f2bf(v.w);
    }
  }
  __syncthreads();
  {  // step 1: head wv: o1[e][p] = sum_d ctxn[e][d] * q[h*32+d][p]
    f32x4 o1a[2][2];
#pragma unroll
    for (int i = 0; i < 2; ++i)
#pragma unroll
      for (int j = 0; j < 2; ++j)
#pragma unroll
        for (int r = 0; r < 4; ++r) o1a[i][j][r] = 0.f;
    const unsigned short* cbase = ctxnT + (size_t)(b * 4 + wv) * 1024;
#pragma unroll
    for (int mt = 0; mt < 2; ++mt) {
      const short8 af = *(const short8*)(cbase + (mt * 16 + lr) * 32 + lg * 8);
#pragma unroll
      for (int nt = 0; nt < 2; ++nt) {
        const short8 bf = *(const short8*)&qT[(nt * 16 + lr) * 136 + wv * 32 + lg * 8];
        o1a[mt][nt] = __builtin_amdgcn_mfma_f32_16x16x32_bf16(af, bf, o1a[mt][nt], 0, 0, 0);
      }
    }
    // write o1 frags transposed: o1T[px][h*32+e]
#pragma unroll
    for (int mt = 0; mt < 2; ++mt)
#pragma unroll
      for (int nt = 0; nt < 2; ++nt)
#pragma unroll
        for (int r = 0; r < 4; ++r) {
          const int e = wv * 32 + mt * 16 + lg * 4 + r;
          o1T[(nt * 16 + lr) * 136 + e] = f2bf(o1a[mt][nt][r]);
        }
  }
  __syncthreads();
  // step 2: y[o][p] for o in [32*wv, +32): A = out_w bf16 (global, L2-hot)
  f32x4 y[2][2];
#pragma unroll
  for (int i = 0; i < 2; ++i)
#pragma unroll
    for (int j = 0; j < 2; ++j)
#pragma unroll
      for (int r = 0; r < 4; ++r) y[i][j][r] = 0.f;
  const unsigned short* wbase = owb + (size_t)(32 * wv + lr) * 128 + lg * 8;
#pragma unroll
  for (int mt = 0; mt < 2; ++mt) {
#pragma unroll
    for (int ks = 0; ks < 4; ++ks) {
      const short8 af = *(const short8*)(wbase + mt * 16 * 128 + ks * 32);
#pragma unroll
      for (int nt = 0; nt < 2; ++nt) {
        const short8 bf = *(const short8*)&o1T[(nt * 16 + lr) * 136 + ks * 32 + lg * 8];
        y[mt][nt] = __builtin_amdgcn_mfma_f32_16x16x32_bf16(af, bf, y[mt][nt], 0, 0, 0);
      }
    }
  }
  // bias + per-pixel sumsq partials
  {
    float ss[2] = {0.f, 0.f};
#pragma unroll
    for (int mt = 0; mt < 2; ++mt)
#pragma unroll
      for (int r = 0; r < 4; ++r) {
        const int row = 32 * wv + mt * 16 + lg * 4 + r;
        const float bb = out_b[row];
#pragma unroll
        for (int nt = 0; nt < 2; ++nt) {
          y[mt][nt][r] += bb;
          ss[nt] = fmaf(y[mt][nt][r], y[mt][nt][r], ss[nt]);
        }
      }
#pragma unroll
    for (int nt = 0; nt < 2; ++nt)
      redu[(wv * 4 + lg) * 32 + nt * 16 + lr] = ss[nt];
  }
  __syncthreads();
  if (t < 32) {
    float s = 0.f;
#pragma unroll
    for (int g = 0; g < 16; ++g) s += redu[g * 32 + t];
    inv[t] = SQRT128 / fmaxf(sqrtf(s), 1e-12f);
  }
  __syncthreads();
  {  // scale + store
    float* ob = io + (size_t)b * 128 * NPIX + p0;
#pragma unroll
    for (int mt = 0; mt < 2; ++mt)
#pragma unroll
      for (int r = 0; r < 4; ++r) {
        const int row = 32 * wv + mt * 16 + lg * 4 + r;
        const float g = out_norm_g[row];
#pragma unroll
        for (int nt = 0; nt < 2; ++nt) {
          const int col = nt * 16 + lr;
          ob[(size_t)row * NPIX + col] = y[mt][nt][r] * inv[col] * g;
        }
      }
  }
}

extern "C" void kernel_launch(void* const* d_in, const int* in_sizes, int n_in,
                              void* d_out, int out_size, void* d_ws, size_t ws_size,
                              hipStream_t stream) {
  const float* x          = (const float*)d_in[0];
  const float* norm_g     = (const float*)d_in[1];
  const float* qkv_w      = (const float*)d_in[2];
  const float* mem_kv     = (const float*)d_in[3];
  const float* out_w      = (const float*)d_in[4];
  const float* out_b      = (const float*)d_in[5];
  const float* out_norm_g = (const float*)d_in[6];
  float* out = (float*)d_out;

  const size_t need = (size_t)(2097152 + 65536 + 24576 + 8192 + 32768) * 4;
  if (ws_size >= need) {
    float* part_ctx = (float*)d_ws;
    float* part_se  = part_ctx + 2097152;
    unsigned short* wbf   = (unsigned short*)(part_se + 65536);
    unsigned short* owb   = (unsigned short*)(part_se + 65536 + 24576);
    unsigned short* ctxnT = (unsigned short*)(part_se + 65536 + 24576 + 8192);
    k_prep<<<48, 256, 0, stream>>>(qkv_w, wbf, 49152);
    k_prep<<<16, 256, 0, stream>>>(out_w, owb, 16384);
    k1<true><<<dim3(32, 16), 256, 0, stream>>>(x, norm_g, wbf, out, part_ctx, part_se);
    k_reduce<<<16, 256, 0, stream>>>(part_ctx, part_se, mem_kv, ctxnT);
    k3<<<dim3(288, 16), 256, 0, stream>>>(ctxnT, owb, out_b, out_norm_g, out);
  } else {
    float* ctxG = (float*)d_ws;
    float* seG  = ctxG + 65536;
    unsigned short* wbf   = (unsigned short*)(seG + 2048);
    unsigned short* owb   = (unsigned short*)(seG + 2048 + 24576);
    unsigned short* ctxnT = (unsigned short*)(seG + 2048 + 24576 + 8192);
    k_prep<<<48, 256, 0, stream>>>(qkv_w, wbf, 49152);
    k_prep<<<16, 256, 0, stream>>>(out_w, owb, 16384);
    k_init<<<64, 256, 0, stream>>>(mem_kv, ctxG, seG);
    k1<false><<<dim3(32, 16), 256, 0, stream>>>(x, norm_g, wbf, out, ctxG, seG);
    k_norm<<<16, 256, 0, stream>>>(ctxG, seG, ctxnT);
    k3<<<dim3(288, 16), 256, 0, stream>>>(ctxnT, owb, out_b, out_norm_g, out);
  }
}

// Round 5
// 114.550 us; speedup vs baseline: 10.6788x; 1.0627x over previous
//
#include <hip/hip_runtime.h>
#include <math.h>

#define NPIX 9216
#define NBLK 48          // k1 blocks per batch (288 tiles / 6 tiles-per-block)
#define TPB 6            // pixel-tiles per k1 block
#define SCALE 0.17677669529663687f   // 32^-0.5
#define SQRT128 11.313708498984761f

typedef __attribute__((ext_vector_type(8))) short short8;
typedef __attribute__((ext_vector_type(4))) float f32x4;

static __device__ __forceinline__ unsigned short f2bf(float f) {
  union { float f; unsigned u; } v; v.f = f;
  return (unsigned short)((v.u + 0x7fffu + ((v.u >> 16) & 1u)) >> 16);
}
static __device__ __forceinline__ float bf2f(unsigned short h) {
  union { unsigned u; float f; } v; v.u = ((unsigned)h) << 16;
  return v.f;
}

// ws layout (f32 units), PART path:
//   part_ctx [16][NBLK][4096] @ 0                     (3,145,728)
//   part_se  [16][NBLK][128]  @ 3145728               (98,304)
//   wbf  bf16[384][128]       @ 3244032               (24,576 f32 slots)
//   owb  bf16[128][128]       @ 3268608               (8,192 f32 slots)
//   ctxnT bf16[16][4][32][32] @ 3276800               (32,768 f32 slots)

// qkv_w * norm_g folded, cvt bf16
__global__ __launch_bounds__(256) void k_prep_g(const float* __restrict__ w,
                                                const float* __restrict__ g,
                                                unsigned short* __restrict__ wb, int n) {
  const int i = blockIdx.x * 256 + threadIdx.x;
  if (i * 4 < n) {
    const int c = (i * 4) & 127;
    const float4 v = *(const float4*)(w + i * 4);
    const float4 gg = *(const float4*)(g + c);
    unsigned long long p = (unsigned long long)f2bf(v.x * gg.x)
                         | ((unsigned long long)f2bf(v.y * gg.y) << 16)
                         | ((unsigned long long)f2bf(v.z * gg.z) << 32)
                         | ((unsigned long long)f2bf(v.w * gg.w) << 48);
    *(unsigned long long*)(wb + i * 4) = p;
  }
}

__global__ __launch_bounds__(256) void k_prep(const float* __restrict__ w,
                                              unsigned short* __restrict__ wb, int n) {
  const int i = blockIdx.x * 256 + threadIdx.x;
  if (i * 4 < n) {
    const float4 v = *(const float4*)(w + i * 4);
    unsigned long long p = (unsigned long long)f2bf(v.x)
                         | ((unsigned long long)f2bf(v.y) << 16)
                         | ((unsigned long long)f2bf(v.z) << 32)
                         | ((unsigned long long)f2bf(v.w) << 48);
    *(unsigned long long*)(wb + i * 4) = p;
  }
}

__global__ __launch_bounds__(256) void k_init(const float* __restrict__ mem_kv,
                                              float* __restrict__ ctxG,
                                              float* __restrict__ sumexpG) {
  const int bh = blockIdx.x;
  const int h = bh & 3;
  const float* mk = mem_kv + h * 128;
  const float* mv = mem_kv + 512 + h * 128;
  const int t = threadIdx.x;
  const int d = t >> 3, e0 = (t & 7) * 4;
  float ek[4], se = 0.f;
#pragma unroll
  for (int j = 0; j < 4; ++j) { ek[j] = __expf(mk[d * 4 + j]); se += ek[j]; }
#pragma unroll
  for (int ei = 0; ei < 4; ++ei) {
    const int e = e0 + ei;
    float s = 0.f;
#pragma unroll
    for (int j = 0; j < 4; ++j) s += ek[j] * mv[e * 4 + j];
    ctxG[(bh * 32 + d) * 32 + e] = s;
  }
  if ((t & 7) == 0) sumexpG[bh * 32 + d] = se;
}

// Fused MFMA k1: x->bf16 transpose load (+sumsq) + QKV GEMM (g folded in W,
// inv applied to C-frags) + q-softmax -> d_out staging + exp(k)v^T ctx partials.
template <bool PART>
__global__ __launch_bounds__(256, 3) void k1(
    const float* __restrict__ x, const unsigned short* __restrict__ wbf,
    float* __restrict__ q_out, float* __restrict__ ctx_dst,
    float* __restrict__ se_dst) {
  // xnT bf16[32][136] (live load->MFMA) overlaps qkv bf16[384][40] (live after)
  __shared__ __align__(16) unsigned char smem[30720 + 4096 + 128];
  unsigned short* xnT = (unsigned short*)smem;
  unsigned short* qkv = (unsigned short*)smem;
  float* redu = (float*)(smem + 30720);   // [32][32]
  float* inv = (float*)(smem + 30720 + 4096);

  const int t = threadIdx.x;
  const int b = blockIdx.y;
  const int blk = blockIdx.x;
  const int wv = t >> 6;
  const int lane = t & 63;
  const int lr = lane & 15;
  const int lg = lane >> 4;
  const int r = t >> 3, c4 = (t & 7) * 4;   // load decomposition

  f32x4 acc[6][2];
  f32x4 ctx[2][2];
#pragma unroll
  for (int i = 0; i < 6; ++i)
#pragma unroll
    for (int j = 0; j < 2; ++j)
#pragma unroll
      for (int q = 0; q < 4; ++q) acc[i][j][q] = 0.f;
#pragma unroll
  for (int i = 0; i < 2; ++i)
#pragma unroll
    for (int j = 0; j < 2; ++j)
#pragma unroll
      for (int q = 0; q < 4; ++q) ctx[i][j][q] = 0.f;
  float se_acc = 0.f;

  for (int it = 0; it < TPB; ++it) {
    const int p0 = (blk * TPB + it) * 32;
    const float* xb = x + ((size_t)b * 128) * NPIX + p0;

    {  // load x -> bf16 transpose into xnT + sumsq partials
      float ss0 = 0.f, ss1 = 0.f, ss2 = 0.f, ss3 = 0.f;
#pragma unroll
      for (int pass = 0; pass < 4; ++pass) {
        const int row = pass * 32 + r;
        const float4 v = *(const float4*)(xb + (size_t)row * NPIX + c4);
        xnT[(c4 + 0) * 136 + row] = f2bf(v.x);
        xnT[(c4 + 1) * 136 + row] = f2bf(v.y);
        xnT[(c4 + 2) * 136 + row] = f2bf(v.z);
        xnT[(c4 + 3) * 136 + row] = f2bf(v.w);
        ss0 = fmaf(v.x, v.x, ss0); ss1 = fmaf(v.y, v.y, ss1);
        ss2 = fmaf(v.z, v.z, ss2); ss3 = fmaf(v.w, v.w, ss3);
      }
      *(float4*)&redu[r * 32 + c4] = make_float4(ss0, ss1, ss2, ss3);
    }
    __syncthreads();  // A: xnT + redu visible
    {  // QKV MFMA (pre-inv); wave 0 lanes<32 concurrently produce inv
      short8 bfr[4][2];
#pragma unroll
      for (int ks = 0; ks < 4; ++ks)
#pragma unroll
        for (int nt = 0; nt < 2; ++nt)
          bfr[ks][nt] = *(const short8*)&xnT[(nt * 16 + lr) * 136 + ks * 32 + lg * 8];
      if (t < 32) {
        float s = 0.f;
#pragma unroll
        for (int g = 0; g < 32; ++g) s += redu[g * 32 + t];
        inv[t] = SQRT128 / fmaxf(sqrtf(s), 1e-12f);
      }
      const unsigned short* wbase = wbf + (size_t)(96 * wv + lr) * 128 + lg * 8;
#pragma unroll
      for (int mt = 0; mt < 6; ++mt) {
#pragma unroll
        for (int ks = 0; ks < 4; ++ks) {
          const short8 af = *(const short8*)(wbase + mt * 16 * 128 + ks * 32);
          acc[mt][0] = __builtin_amdgcn_mfma_f32_16x16x32_bf16(af, bfr[ks][0], acc[mt][0], 0, 0, 0);
          acc[mt][1] = __builtin_amdgcn_mfma_f32_16x16x32_bf16(af, bfr[ks][1], acc[mt][1], 0, 0, 0);
        }
      }
    }
    __syncthreads();  // B: xnT reads done (qkv may overwrite), inv visible
    {  // scale C-frags by inv[pixel], write qkv bf16 [384][40]
      const float iv0 = inv[lr], iv1 = inv[16 + lr];
#pragma unroll
      for (int mt = 0; mt < 6; ++mt)
#pragma unroll
        for (int nt = 0; nt < 2; ++nt) {
          const float iv = nt ? iv1 : iv0;
#pragma unroll
          for (int q = 0; q < 4; ++q) {
            const int row = 96 * wv + mt * 16 + lg * 4 + q;
            qkv[row * 40 + nt * 16 + lr] = f2bf(acc[mt][nt][q] * iv);
            acc[mt][nt][q] = 0.f;
          }
        }
    }
    __syncthreads();  // C: qkv visible
    if (t < 128) {
      // exp(k) full row + row-sum accumulate (rows 128..255)
      const int row = 128 + t;
      float s = 0.f;
#pragma unroll
      for (int i = 0; i < 32; ++i) {
        const float v = __expf(bf2f(qkv[row * 40 + i]));
        qkv[row * 40 + i] = f2bf(v);
        s += v;
      }
      se_acc += s;
    } else {
      // q softmax over d, *scale, stage into d_out
      const int idx = t - 128, h = idx >> 5, p = idx & 31;
      float qv[32], m = -1e30f;
#pragma unroll
      for (int d = 0; d < 32; ++d) { qv[d] = bf2f(qkv[(h * 32 + d) * 40 + p]); m = fmaxf(m, qv[d]); }
      float s = 0.f;
#pragma unroll
      for (int d = 0; d < 32; ++d) { qv[d] = __expf(qv[d] - m); s += qv[d]; }
      const float rs = SCALE / s;
      float* qo = q_out + ((size_t)b * 128 + h * 32) * NPIX + p0 + p;
#pragma unroll
      for (int d = 0; d < 32; ++d) qo[(size_t)d * NPIX] = qv[d] * rs;
    }
    __syncthreads();  // D: exp(k) visible
    {  // ctx MFMA: head = wv
#pragma unroll
      for (int dt = 0; dt < 2; ++dt) {
        const short8 af = *(const short8*)&qkv[(128 + wv * 32 + dt * 16 + lr) * 40 + lg * 8];
#pragma unroll
        for (int et = 0; et < 2; ++et) {
          const short8 bf = *(const short8*)&qkv[(256 + wv * 32 + et * 16 + lr) * 40 + lg * 8];
          ctx[dt][et] = __builtin_amdgcn_mfma_f32_16x16x32_bf16(af, bf, ctx[dt][et], 0, 0, 0);
        }
      }
    }
    // no barrier: next load writes xnT bytes [0,8704) / redu; phase-6 reads
    // qkv bytes >= 10240; q-row reads finished before barrier D.
  }

  if (PART) {
    float* dst = ctx_dst + ((size_t)(b * NBLK + blk)) * 4096 + wv * 1024;
#pragma unroll
    for (int dt = 0; dt < 2; ++dt)
#pragma unroll
      for (int et = 0; et < 2; ++et)
#pragma unroll
        for (int q = 0; q < 4; ++q)
          dst[(dt * 16 + lg * 4 + q) * 32 + et * 16 + lr] = ctx[dt][et][q];
    if (t < 128) se_dst[(b * NBLK + blk) * 128 + t] = se_acc;
  } else {
#pragma unroll
    for (int dt = 0; dt < 2; ++dt)
#pragma unroll
      for (int et = 0; et < 2; ++et)
#pragma unroll
        for (int q = 0; q < 4; ++q)
          atomicAdd(&ctx_dst[((size_t)b * 128 + wv * 32 + dt * 16 + lg * 4 + q) * 32 + et * 16 + lr],
                    ctx[dt][et][q]);
    if (t < 128) atomicAdd(&se_dst[b * 128 + t], se_acc);
  }
}

// Reduce NBLK partials + mem_kv -> normalized transposed bf16 ctx ctxnT[b][h][e][d]
__global__ __launch_bounds__(256) void k_reduce(
    const float* __restrict__ part_ctx, const float* __restrict__ part_se,
    const float* __restrict__ mem_kv, unsigned short* __restrict__ ctxnT) {
  const int bh = blockIdx.x;          // b*4+h
  const int b = bh >> 2, h = bh & 3;
  const int t = threadIdx.x;
  const int d = t >> 3, e4 = (t & 7) * 4;

  const float* mk = mem_kv + h * 128 + d * 4;
  const float* mv = mem_kv + 512 + h * 128;
  float ek[4];
  float se = 0.f;
#pragma unroll
  for (int j = 0; j < 4; ++j) { ek[j] = __expf(mk[j]); se += ek[j]; }
  float acc[4];
#pragma unroll
  for (int i = 0; i < 4; ++i) {
    float s = 0.f;
#pragma unroll
    for (int j = 0; j < 4; ++j) s += ek[j] * mv[(e4 + i) * 4 + j];
    acc[i] = s;
  }
  const float* src = part_ctx + ((size_t)b * NBLK) * 4096 + h * 1024 + d * 32 + e4;
  for (int p = 0; p < NBLK; ++p) {
    const float4 v = *(const float4*)(src + (size_t)p * 4096);
    acc[0] += v.x; acc[1] += v.y; acc[2] += v.z; acc[3] += v.w;
  }
  for (int p = 0; p < NBLK; ++p)
    se += part_se[((size_t)b * NBLK + p) * 128 + h * 32 + d];
  const float ise = 1.f / se;
  unsigned short* dst = ctxnT + (size_t)bh * 1024;
#pragma unroll
  for (int i = 0; i < 4; ++i)
    dst[(e4 + i) * 32 + d] = f2bf(acc[i] * ise);
}

// Fallback-path normalizer: ctxG/seG (f32) -> ctxnT bf16
__global__ __launch_bounds__(256) void k_norm(
    const float* __restrict__ ctxG, const float* __restrict__ seG,
    unsigned short* __restrict__ ctxnT) {
  const int b = blockIdx.x;
  const int t = threadIdx.x;
  const int h = t >> 6, d = (t >> 1) & 31, e0 = (t & 1) * 16;
  const int r = h * 32 + d;
  const float ise = 1.f / seG[b * 128 + r];
  const float* src = ctxG + ((size_t)b * 128 + r) * 32;
  unsigned short* dst = ctxnT + ((size_t)(b * 4 + h) * 32) * 32;
#pragma unroll
  for (int i = 0; i < 16; ++i)
    dst[(e0 + i) * 32 + d] = f2bf(src[e0 + i] * ise);
}

// MFMA k3: q->bf16 transpose + (ctxn^T q) MFMA + out-proj MFMA + bias + rmsnorm
__global__ __launch_bounds__(256) void k3(
    const unsigned short* __restrict__ ctxnT, const unsigned short* __restrict__ owb,
    const float* __restrict__ out_b, const float* __restrict__ out_norm_g,
    float* __restrict__ io) {
  __shared__ __align__(16) unsigned char smem[8704 + 8704 + 2048 + 128];
  unsigned short* qT = (unsigned short*)smem;                 // [32 px][136 ch]
  unsigned short* o1T = (unsigned short*)(smem + 8704);       // [32 px][136 ch]
  float* redu = (float*)(smem + 8704 + 8704);                 // [16][32]
  float* inv = (float*)(smem + 8704 + 8704 + 2048);           // [32]

  const int t = threadIdx.x;
  const int b = blockIdx.y;
  const int p0 = blockIdx.x * 32;
  const int wv = t >> 6;
  const int lane = t & 63;
  const int lr = lane & 15;
  const int lg = lane >> 4;

  {  // load q tile f32 [128 ch][32 px] -> qT bf16 [px][ch]
    const float* qb = io + (size_t)b * 128 * NPIX + p0;
    const int r = t >> 3, c4 = (t & 7) * 4;
#pragma unroll
    for (int pass = 0; pass < 4; ++pass) {
      const int row = pass * 32 + r;
      const float4 v = *(const float4*)(qb + (size_t)row * NPIX + c4);
      qT[(c4 + 0) * 136 + row] = f2bf(v.x);
      qT[(c4 + 1) * 136 + row] = f2bf(v.y);
      qT[(c4 + 2) * 136 + row] = f2bf(v.z);
      qT[(c4 + 3) * 136 + row] = f2bf(v.w);
    }
  }
  __syncthreads();
  {  // step 1: head wv: o1[e][p] = sum_d ctxn[e][d] * q[h*32+d][p]
    f32x4 o1a[2][2];
#pragma unroll
    for (int i = 0; i < 2; ++i)
#pragma unroll
      for (int j = 0; j < 2; ++j)
#pragma unroll
        for (int q = 0; q < 4; ++q) o1a[i][j][q] = 0.f;
    const unsigned short* cbase = ctxnT + (size_t)(b * 4 + wv) * 1024;
#pragma unroll
    for (int mt = 0; mt < 2; ++mt) {
      const short8 af = *(const short8*)(cbase + (mt * 16 + lr) * 32 + lg * 8);
#pragma unroll
      for (int nt = 0; nt < 2; ++nt) {
        const short8 bf = *(const short8*)&qT[(nt * 16 + lr) * 136 + wv * 32 + lg * 8];
        o1a[mt][nt] = __builtin_amdgcn_mfma_f32_16x16x32_bf16(af, bf, o1a[mt][nt], 0, 0, 0);
      }
    }
#pragma unroll
    for (int mt = 0; mt < 2; ++mt)
#pragma unroll
      for (int nt = 0; nt < 2; ++nt)
#pragma unroll
        for (int q = 0; q < 4; ++q) {
          const int e = wv * 32 + mt * 16 + lg * 4 + q;
          o1T[(nt * 16 + lr) * 136 + e] = f2bf(o1a[mt][nt][q]);
        }
  }
  __syncthreads();
  // step 2: y[o][p] for o in [32*wv, +32)
  f32x4 y[2][2];
#pragma unroll
  for (int i = 0; i < 2; ++i)
#pragma unroll
    for (int j = 0; j < 2; ++j)
#pragma unroll
      for (int q = 0; q < 4; ++q) y[i][j][q] = 0.f;
  const unsigned short* wbase = owb + (size_t)(32 * wv + lr) * 128 + lg * 8;
#pragma unroll
  for (int mt = 0; mt < 2; ++mt) {
#pragma unroll
    for (int ks = 0; ks < 4; ++ks) {
      const short8 af = *(const short8*)(wbase + mt * 16 * 128 + ks * 32);
#pragma unroll
      for (int nt = 0; nt < 2; ++nt) {
        const short8 bf = *(const short8*)&o1T[(nt * 16 + lr) * 136 + ks * 32 + lg * 8];
        y[mt][nt] = __builtin_amdgcn_mfma_f32_16x16x32_bf16(af, bf, y[mt][nt], 0, 0, 0);
      }
    }
  }
  {
    float ss[2] = {0.f, 0.f};
#pragma unroll
    for (int mt = 0; mt < 2; ++mt)
#pragma unroll
      for (int q = 0; q < 4; ++q) {
        const int row = 32 * wv + mt * 16 + lg * 4 + q;
        const float bb = out_b[row];
#pragma unroll
        for (int nt = 0; nt < 2; ++nt) {
          y[mt][nt][q] += bb;
          ss[nt] = fmaf(y[mt][nt][q], y[mt][nt][q], ss[nt]);
        }
      }
#pragma unroll
    for (int nt = 0; nt < 2; ++nt)
      redu[(wv * 4 + lg) * 32 + nt * 16 + lr] = ss[nt];
  }
  __syncthreads();
  if (t < 32) {
    float s = 0.f;
#pragma unroll
    for (int g = 0; g < 16; ++g) s += redu[g * 32 + t];
    inv[t] = SQRT128 / fmaxf(sqrtf(s), 1e-12f);
  }
  __syncthreads();
  {
    float* ob = io + (size_t)b * 128 * NPIX + p0;
#pragma unroll
    for (int mt = 0; mt < 2; ++mt)
#pragma unroll
      for (int q = 0; q < 4; ++q) {
        const int row = 32 * wv + mt * 16 + lg * 4 + q;
        const float g = out_norm_g[row];
#pragma unroll
        for (int nt = 0; nt < 2; ++nt) {
          const int col = nt * 16 + lr;
          ob[(size_t)row * NPIX + col] = y[mt][nt][q] * inv[col] * g;
        }
      }
  }
}

extern "C" void kernel_launch(void* const* d_in, const int* in_sizes, int n_in,
                              void* d_out, int out_size, void* d_ws, size_t ws_size,
                              hipStream_t stream) {
  const float* x          = (const float*)d_in[0];
  const float* norm_g     = (const float*)d_in[1];
  const float* qkv_w      = (const float*)d_in[2];
  const float* mem_kv     = (const float*)d_in[3];
  const float* out_w      = (const float*)d_in[4];
  const float* out_b      = (const float*)d_in[5];
  const float* out_norm_g = (const float*)d_in[6];
  float* out = (float*)d_out;

  const size_t PC = (size_t)NBLK * 16 * 4096;
  const size_t PS = (size_t)NBLK * 16 * 128;
  const size_t need = (PC + PS + 24576 + 8192 + 32768) * 4;
  if (ws_size >= need) {
    float* part_ctx = (float*)d_ws;
    float* part_se  = part_ctx + PC;
    unsigned short* wbf   = (unsigned short*)(part_se + PS);
    unsigned short* owb   = (unsigned short*)(part_se + PS + 24576);
    unsigned short* ctxnT = (unsigned short*)(part_se + PS + 24576 + 8192);
    k_prep_g<<<48, 256, 0, stream>>>(qkv_w, norm_g, wbf, 49152);
    k_prep<<<16, 256, 0, stream>>>(out_w, owb, 16384);
    k1<true><<<dim3(NBLK, 16), 256, 0, stream>>>(x, wbf, out, part_ctx, part_se);
    k_reduce<<<64, 256, 0, stream>>>(part_ctx, part_se, mem_kv, ctxnT);
    k3<<<dim3(288, 16), 256, 0, stream>>>(ctxnT, owb, out_b, out_norm_g, out);
  } else {
    float* ctxG = (float*)d_ws;
    float* seG  = ctxG + 65536;
    unsigned short* wbf   = (unsigned short*)(seG + 2048);
    unsigned short* owb   = (unsigned short*)(seG + 2048 + 24576);
    unsigned short* ctxnT = (unsigned short*)(seG + 2048 + 24576 + 8192);
    k_prep_g<<<48, 256, 0, stream>>>(qkv_w, norm_g, wbf, 49152);
    k_prep<<<16, 256, 0, stream>>>(out_w, owb, 16384);
    k_init<<<64, 256, 0, stream>>>(mem_kv, ctxG, seG);
    k1<false><<<dim3(NBLK, 16), 256, 0, stream>>>(x, wbf, out, ctxG, seG);
    k_norm<<<16, 256, 0, stream>>>(ctxG, seG, ctxnT);
    k3<<<dim3(288, 16), 256, 0, stream>>>(ctxnT, owb, out_b, out_norm_g, out);
  }
}